// Round 1
// 70.694 us; speedup vs baseline: 1.0258x; 1.0258x over previous
//
#include <hip/hip_runtime.h>

// JetECF, beta=2. Established facts (R0-R8):
//  - Output fp32; harness bf16-rounds both sides. ecf2 must replicate numpy's
//    fp32 op order BIT-EXACTLY (immutable): per column j, sequential ascending
//    i, single fp32 acc, ops fl(fl(fl(de^2)+fl(dp^2))*pt_i); final sum over j
//    ascending, single fp32 acc. ecf1/ecf3 via exact fp64 rank-4 identity.
//  - Harness floor ~64.7us (d_ws poison fill + resets); kernel ~7.8us,
//    VALU-issue-bound (Phase B ~3080 scalar VALU/wave).
//
// R9 change: pack Phase B 2-wide on the v_pk_*_f32 pipe (inline asm; ISel
// won't emit these from <2 x float>, per R7).
//  - i-side uniforms staged to LDS once; per step ds_read2_b32 off0:i off1:i
//    gives [v_i,v_i] pairs (LDS pipe, no VALU broadcast cost). Cross-i pairs
//    [v_a,v_b] use off0:a off1:b.  5-deep prefetch, counted lgkmcnt.
//  - de via v_pk_fma_f32(pe, -1, e): exact == __fsub_rn (no neg-modifier risk).
//  - Segment schedule (each slot's own i stays ascending => bit-exact):
//      G=0..6   : pk(s0,s1)@i=G (s0 masked in HIP) + pk(s2,s3)@i=G
//      G=7      : pk(s2,s3)@7 + s1@7 scalar (HIP)
//      G=8..71  : pk(s2,s3)@G
//      G=72..134: pk(s1@G-64 masked-HIP, s3@G)   [s2 deferred]
//      G=135    : s3@135 scalar (HIP)
//      G=136..198: pk(s2@G-64, s3@G), SAME pred (v<lane) => exec-mask trick,
//                  s_mov exec with compile-time literal (2 SALU, 0 VALU).
//    Phase B VALU ~3080 -> ~1700 per wave.  Predicted kernel ~5us.

constexpr int NPART = 200;
typedef float f2 __attribute__((ext_vector_type(2)));

__device__ __forceinline__ float bcast(float v, int ii) {
    return __int_as_float(__builtin_amdgcn_readlane(__float_as_int(v), ii));
}

constexpr int offA(int g) {
    return (g < 72) ? g : (g == 135 ? 135 : g - 64);
}

struct Ctx {
    f2 bw[5], be[5], bp[5];           // prefetch buffers (rotating, idx G%5)
    f2 acc23, accY, tt;
    f2 pe01, pp01, pe23, pp23, pe13, pp13, n1;
    float a0, a1, a2, a3;
    float pe1, pp1, pe3, pp3;
    unsigned aw, ae, ap;              // LDS byte addresses of w/e/p arrays
    int lane;
};

template <int G>
__device__ __forceinline__ void prefetch(Ctx& c) {
    constexpr int A = offA(G), B = G, S = G % 5;
    asm volatile(
        "ds_read2_b32 %[w], %[aw] offset0:%c[A] offset1:%c[B]\n\t"
        "ds_read2_b32 %[e], %[ae] offset0:%c[A] offset1:%c[B]\n\t"
        "ds_read2_b32 %[p], %[ap] offset0:%c[A] offset1:%c[B]\n\t"
        : [w] "+v"(c.bw[S]), [e] "+v"(c.be[S]), [p] "+v"(c.bp[S])
        : [aw] "v"(c.aw), [ae] "v"(c.ae), [ap] "v"(c.ap), [A] "i"(A), [B] "i"(B));
}

template <int G>
__device__ __forceinline__ void cstep(Ctx& c) {
    constexpr int rem = 198 - G;
    constexpr int K = 3 * (rem < 4 ? rem : 4);   // outstanding ds ops allowed
    constexpr int S = G % 5;
    if constexpr (G <= 6) {
        f2 t1, t2;
        asm volatile(
            "s_waitcnt lgkmcnt(%c[K])\n\t"
            "v_pk_fma_f32 %[t1], %[pe01], %[n1], %[be]\n\t"
            "v_pk_fma_f32 %[t2], %[pp01], %[n1], %[bp]\n\t"
            "v_pk_mul_f32 %[t1], %[t1], %[t1]\n\t"
            "v_pk_mul_f32 %[t2], %[t2], %[t2]\n\t"
            "v_pk_add_f32 %[t1], %[t1], %[t2]\n\t"
            "v_pk_mul_f32 %[tt], %[t1], %[bw]\n\t"
            "v_pk_fma_f32 %[t1], %[pe23], %[n1], %[be]\n\t"
            "v_pk_fma_f32 %[t2], %[pp23], %[n1], %[bp]\n\t"
            "v_pk_mul_f32 %[t1], %[t1], %[t1]\n\t"
            "v_pk_mul_f32 %[t2], %[t2], %[t2]\n\t"
            "v_pk_add_f32 %[t1], %[t1], %[t2]\n\t"
            "v_pk_mul_f32 %[t1], %[t1], %[bw]\n\t"
            "v_pk_add_f32 %[acc], %[acc], %[t1]\n\t"
            : [t1] "=&v"(t1), [t2] "=&v"(t2), [tt] "=&v"(c.tt),
              [acc] "+v"(c.acc23), [bw] "+v"(c.bw[S]), [be] "+v"(c.be[S]),
              [bp] "+v"(c.bp[S])
            : [pe01] "v"(c.pe01), [pp01] "v"(c.pp01), [pe23] "v"(c.pe23),
              [pp23] "v"(c.pp23), [n1] "v"(c.n1), [K] "i"(K));
        c.a1 = __fadd_rn(c.a1, c.tt.y);
        c.a0 = __fadd_rn(c.a0, (G < c.lane) ? c.tt.x : 0.0f);
    } else if constexpr (G <= 71) {
        f2 t1, t2;
        asm volatile(
            "s_waitcnt lgkmcnt(%c[K])\n\t"
            "v_pk_fma_f32 %[t1], %[pe23], %[n1], %[be]\n\t"
            "v_pk_fma_f32 %[t2], %[pp23], %[n1], %[bp]\n\t"
            "v_pk_mul_f32 %[t1], %[t1], %[t1]\n\t"
            "v_pk_mul_f32 %[t2], %[t2], %[t2]\n\t"
            "v_pk_add_f32 %[t1], %[t1], %[t2]\n\t"
            "v_pk_mul_f32 %[t1], %[t1], %[bw]\n\t"
            "v_pk_add_f32 %[acc], %[acc], %[t1]\n\t"
            : [t1] "=&v"(t1), [t2] "=&v"(t2), [acc] "+v"(c.acc23),
              [bw] "+v"(c.bw[S]), [be] "+v"(c.be[S]), [bp] "+v"(c.bp[S])
            : [pe23] "v"(c.pe23), [pp23] "v"(c.pp23), [n1] "v"(c.n1), [K] "i"(K));
        if constexpr (G == 7) {  // s1@7, unpredicated, np scalar order
            const float de = __fsub_rn(c.be[S].x, c.pe1);
            const float dp = __fsub_rn(c.bp[S].x, c.pp1);
            const float r2 = __fadd_rn(__fmul_rn(de, de), __fmul_rn(dp, dp));
            c.a1 = __fadd_rn(c.a1, __fmul_rn(r2, c.bw[S].x));
        }
    } else if constexpr (G <= 134) {
        if constexpr (G == 72) { c.a2 = c.acc23.x; c.a3 = c.acc23.y; }
        f2 t1, t2;
        asm volatile(
            "s_waitcnt lgkmcnt(%c[K])\n\t"
            "v_pk_fma_f32 %[t1], %[pe13], %[n1], %[be]\n\t"
            "v_pk_fma_f32 %[t2], %[pp13], %[n1], %[bp]\n\t"
            "v_pk_mul_f32 %[t1], %[t1], %[t1]\n\t"
            "v_pk_mul_f32 %[t2], %[t2], %[t2]\n\t"
            "v_pk_add_f32 %[t1], %[t1], %[t2]\n\t"
            "v_pk_mul_f32 %[tt], %[t1], %[bw]\n\t"
            : [t1] "=&v"(t1), [t2] "=&v"(t2), [tt] "=&v"(c.tt),
              [bw] "+v"(c.bw[S]), [be] "+v"(c.be[S]), [bp] "+v"(c.bp[S])
            : [pe13] "v"(c.pe13), [pp13] "v"(c.pp13), [n1] "v"(c.n1), [K] "i"(K));
        c.a3 = __fadd_rn(c.a3, c.tt.y);                              // s3@G
        c.a1 = __fadd_rn(c.a1, ((G - 72) < c.lane) ? c.tt.x : 0.0f); // s1@G-64
    } else if constexpr (G == 135) {
        asm volatile("s_waitcnt lgkmcnt(%c[K])"
                     : [bw] "+v"(c.bw[S]), [be] "+v"(c.be[S]), [bp] "+v"(c.bp[S])
                     : [K] "i"(K));
        const float de = __fsub_rn(c.be[S].x, c.pe3);
        const float dp = __fsub_rn(c.bp[S].x, c.pp3);
        const float r2 = __fadd_rn(__fmul_rn(de, de), __fmul_rn(dp, dp));
        c.a3 = __fadd_rn(c.a3, __fmul_rn(r2, c.bw[S].x));
    } else {
        if constexpr (G == 136) { c.accY.x = c.a2; c.accY.y = c.a3; }
        constexpr unsigned sh = G - 135;  // v+1, 1..63; active lanes: lane > v
        constexpr unsigned lm = sh < 32 ? (0xFFFFFFFFu << sh) : 0u;
        constexpr unsigned hm = sh < 32 ? 0xFFFFFFFFu : (0xFFFFFFFFu << (sh - 32));
        f2 t1, t2;
        asm volatile(
            "s_waitcnt lgkmcnt(%c[K])\n\t"
            "s_mov_b32 exec_lo, %c[LM]\n\t"
            "s_mov_b32 exec_hi, %c[HM]\n\t"
            "v_pk_fma_f32 %[t1], %[pe23], %[n1], %[be]\n\t"
            "v_pk_fma_f32 %[t2], %[pp23], %[n1], %[bp]\n\t"
            "v_pk_mul_f32 %[t1], %[t1], %[t1]\n\t"
            "v_pk_mul_f32 %[t2], %[t2], %[t2]\n\t"
            "v_pk_add_f32 %[t1], %[t1], %[t2]\n\t"
            "v_pk_mul_f32 %[t1], %[t1], %[bw]\n\t"
            "v_pk_add_f32 %[acc], %[acc], %[t1]\n\t"
            "s_mov_b64 exec, -1\n\t"
            : [t1] "=&v"(t1), [t2] "=&v"(t2), [acc] "+v"(c.accY),
              [bw] "+v"(c.bw[S]), [be] "+v"(c.be[S]), [bp] "+v"(c.bp[S])
            : [pe23] "v"(c.pe23), [pp23] "v"(c.pp23), [n1] "v"(c.n1),
              [K] "i"(K), [LM] "i"(lm), [HM] "i"(hm));
    }
}

template <int G>
__device__ __forceinline__ void run(Ctx& c) {
    if constexpr (G <= 198) {
        cstep<G>(c);
        if constexpr (G + 5 <= 198) prefetch<G + 5>(c);
        run<G + 1>(c);
    }
}

__global__ __launch_bounds__(64) void jet_ecf_kernel(const float* __restrict__ x,
                                                     float* __restrict__ out,
                                                     int njet) {
#pragma clang fp contract(off)
    const int jet = blockIdx.x;
    if (jet >= njet) return;
    const int lane = threadIdx.x;
    const float* xj = x + (size_t)jet * NPART * 3;

    __shared__ float lds[600];  // SoA: w[0..199], e[200..399], p[400..599]

    // Slot register loads: slot0: j=lane (lanes 0..7), slot1: j=8+lane,
    // slot2: j=72+lane, slot3: j=136+lane. Dummy lanes zero-padded.
    float pw[4], pea[4], ppa[4];
    {
        const int base[4] = {0, 8, 72, 136};
        #pragma unroll
        for (int k = 0; k < 4; ++k) {
            const int p = base[k] + lane;
            const bool valid = (k > 0) || (lane < 8);
            if (valid) {
                pw[k] = xj[p * 3 + 0];
                pea[k] = xj[p * 3 + 1];
                ppa[k] = xj[p * 3 + 2];
            } else {
                pw[k] = 0.0f; pea[k] = 0.0f; ppa[k] = 0.0f;
            }
        }
    }

    // LDS staging of i-side values (uniform source for all lanes' pk pairs).
    #pragma unroll
    for (int r = 0; r < 4; ++r) {
        const int i = lane + (r << 6);
        if (i < NPART) {
            lds[i]       = xj[3 * i + 0];
            lds[200 + i] = xj[3 * i + 1];
            lds[400 + i] = xj[3 * i + 2];
        }
    }

    // ---- Phase A: exact fp64 moments (ecf1, ecf3). Overlaps staging latency.
    double S = 0, Sa = 0, Se = 0, Sp = 0, Saa = 0;
    double Sae = 0, Sap = 0, See = 0, Spp = 0, Sep = 0;
    #pragma unroll
    for (int k = 0; k < 4; ++k) {
        const double w = (double)pw[k];
        const double e = (double)pea[k];
        const double f = (double)ppa[k];
        const double a = e * e + f * f;
        S   += w;        Sa  += w * a;     Se  += w * e;
        Sp  += w * f;    Saa += w * a * a; Sae += w * a * e;
        Sap += w * a * f; See += w * e * e; Spp += w * f * f;
        Sep += w * e * f;
    }
    #pragma unroll
    for (int off = 32; off > 0; off >>= 1) {
        S   += __shfl_down(S,   off, 64);
        Sa  += __shfl_down(Sa,  off, 64);
        Se  += __shfl_down(Se,  off, 64);
        Sp  += __shfl_down(Sp,  off, 64);
        Saa += __shfl_down(Saa, off, 64);
        Sae += __shfl_down(Sae, off, 64);
        Sap += __shfl_down(Sap, off, 64);
        See += __shfl_down(See, off, 64);
        Spp += __shfl_down(Spp, off, 64);
        Sep += __shfl_down(Sep, off, 64);
    }

    __syncthreads();
    asm volatile("" ::: "memory");  // keep LDS stores (asm reads them)
    // Pin Phase A results here; then hard boundary so no Phase A lgkm ops
    // (shuffles) can drift into the counted Phase B region.
    asm volatile("" :: "v"(S), "v"(Sa), "v"(Se), "v"(Sp), "v"(Saa),
                       "v"(Sae), "v"(Sap), "v"(See), "v"(Spp), "v"(Sep));
    __builtin_amdgcn_sched_barrier(0);
    asm volatile("s_waitcnt lgkmcnt(0)" ::: );

    // ---- Phase B: np-order fp32 column sums, packed 2-wide.
    Ctx c;
    c.lane = lane;
    c.aw = (unsigned)(uintptr_t)&lds[0];
    c.ae = (unsigned)(uintptr_t)&lds[200];
    c.ap = (unsigned)(uintptr_t)&lds[400];
    c.n1.x = -1.0f; c.n1.y = -1.0f;
    c.pe01.x = pea[0]; c.pe01.y = pea[1];
    c.pp01.x = ppa[0]; c.pp01.y = ppa[1];
    c.pe23.x = pea[2]; c.pe23.y = pea[3];
    c.pp23.x = ppa[2]; c.pp23.y = ppa[3];
    c.pe13.x = pea[1]; c.pe13.y = pea[3];
    c.pp13.x = ppa[1]; c.pp13.y = ppa[3];
    c.pe1 = pea[1]; c.pp1 = ppa[1]; c.pe3 = pea[3]; c.pp3 = ppa[3];
    c.acc23.x = 0.0f; c.acc23.y = 0.0f;
    c.accY.x = 0.0f;  c.accY.y = 0.0f;
    c.tt.x = 0.0f;    c.tt.y = 0.0f;
    c.a0 = c.a1 = c.a2 = c.a3 = 0.0f;
    #pragma unroll
    for (int k = 0; k < 5; ++k) {
        c.bw[k].x = 0.0f; c.bw[k].y = 0.0f;
        c.be[k].x = 0.0f; c.be[k].y = 0.0f;
        c.bp[k].x = 0.0f; c.bp[k].y = 0.0f;
    }

    prefetch<0>(c); prefetch<1>(c); prefetch<2>(c); prefetch<3>(c); prefetch<4>(c);
    run<0>(c);
    c.a2 = c.accY.x; c.a3 = c.accY.y;

    // t_j = fl(pt_j * s_j)
    const float t0 = __fmul_rn(pw[0], c.a0);
    const float t1 = __fmul_rn(pw[1], c.a1);
    const float t2 = __fmul_rn(pw[2], c.a2);
    const float t3 = __fmul_rn(pw[3], c.a3);

    // Final np step: ecf2 = sum_j fl(pt_j*s_j), sequential ascending j.
    float e2f = 0.0f;
    #pragma unroll
    for (int ii = 0; ii < 8; ++ii)  e2f = __fadd_rn(e2f, bcast(t0, ii));
    #pragma unroll 8
    for (int ii = 0; ii < 64; ++ii) e2f = __fadd_rn(e2f, bcast(t1, ii));
    #pragma unroll 8
    for (int ii = 0; ii < 64; ++ii) e2f = __fadd_rn(e2f, bcast(t2, ii));
    #pragma unroll 8
    for (int ii = 0; ii < 64; ++ii) e2f = __fadd_rn(e2f, bcast(t3, ii));

    if (lane == 0) {
        const double A[4][4] = {
            {  Saa,        Sa,       -2.0 * Sae, -2.0 * Sap },
            {  Sa,         S,        -2.0 * Se,  -2.0 * Sp  },
            { -2.0 * Sae, -2.0 * Se,  4.0 * See,  4.0 * Sep },
            { -2.0 * Sap, -2.0 * Sp,  4.0 * Sep,  4.0 * Spp }
        };
        const double B[4][4] = {
            { Sa,  S,  -2.0 * Se,  -2.0 * Sp  },
            { Saa, Sa, -2.0 * Sae, -2.0 * Sap },
            { Sae, Se, -2.0 * See, -2.0 * Sep },
            { Sap, Sp, -2.0 * Sep, -2.0 * Spp }
        };
        const double C[4][4] = {
            { S,  Sa,  Se,  Sp  },
            { Sa, Saa, Sae, Sap },
            { Se, Sae, See, Sep },
            { Sp, Sap, Sep, Spp }
        };
        double T = 0.0;
        #pragma unroll
        for (int b = 0; b < 4; ++b) {
            #pragma unroll
            for (int g = 0; g < 4; ++g) {
                double ab = 0.0;
                #pragma unroll
                for (int al = 0; al < 4; ++al) ab += A[al][b] * B[al][g];
                T += ab * C[b][g];
            }
        }
        const double ecf1 = S;
        const double ecf2 = (double)e2f;
        const double ecf3 = T * (1.0 / 6.0);
        const double d2 = ecf3 * ecf1 * ecf1 * ecf1 / (ecf2 * ecf2 * ecf2 + 1e-7);
        float4 o = make_float4((float)ecf1, (float)ecf2, (float)ecf3, (float)d2);
        *reinterpret_cast<float4*>(out + (size_t)jet * 4) = o;
    }
}

extern "C" void kernel_launch(void* const* d_in, const int* in_sizes, int n_in,
                              void* d_out, int out_size, void* d_ws, size_t ws_size,
                              hipStream_t stream) {
    const float* x = (const float*)d_in[0];
    float* out = (float*)d_out;
    const int njet = in_sizes[0] / (NPART * 3);
    jet_ecf_kernel<<<njet, 64, 0, stream>>>(x, out, njet);
}

// Round 3
// 69.701 us; speedup vs baseline: 1.0404x; 1.0142x over previous
//
#include <hip/hip_runtime.h>

// JetECF, beta=2. Established facts (R0-R9):
//  - Output fp32; harness bf16-rounds both sides. ecf2 must replicate numpy's
//    fp32 op order BIT-EXACTLY (immutable): per column j, sequential ascending
//    i, single fp32 acc, ops fl(fl(fl(de^2)+fl(dp^2))*pt_i); final sum over j
//    ascending, single fp32 acc. ecf1/ecf3 via exact fp64 rank-4 identity
//    (oracle: any fp64-accurate variant OK).
//  - Harness floor ~64.7us; R9 kernel ~6.0us. v_pk_*_f32 = 2-cyc wave64
//    (confirmed by R9's -1.8us). Phase B pk stream (~1365 pk) is at the
//    semantic floor (412 col-steps minimal; no fma fusion allowed).
//
// R11 = R10 resubmit (R10 bench died with "container failed twice" — infra,
// no counters). One hardening fix: explicit lgkmcnt(0)+memory fence between
// the t_j LDS stores and the e2f float4 read loop (was relying on same-wave
// DS in-order retirement; now explicit).
// R10 changes (attack the ~2000 non-pk cycles/wave):
//  1. Phase A: explicit fp64 fma() restructure (fp contract(off) was
//     de-fusing it): ~112 -> 60 fp64 ops.
//  2. Seg D: pk accumulator accM=[a1,a3]; in-asm cndmask on explicitly
//     clobbered v[40:41] pair + single pk_add (7pk+2sc vs 6pk+4sc).
//  3. e2f: t_j via LDS (stores at finalization hooks G=6/134/end) +
//     50x ds_read_b128 + 200 adds, replacing 200 readlane + 200 add.
//     Same values, same ascending-j order => bit-exact.
//     Hook ds_writes between counted lgkmcnt csteps are safe: extra
//     outstanding lgkm ops only make lgkmcnt(12) more conservative.

constexpr int NPART = 200;
typedef float f2 __attribute__((ext_vector_type(2)));

constexpr int offA(int g) {
    return (g < 72) ? g : (g == 135 ? 135 : g - 64);
}

struct Ctx {
    f2 bw[5], be[5], bp[5];           // prefetch buffers (rotating, idx G%5)
    f2 acc23, accY, accM, tt;
    f2 pe01, pp01, pe23, pp23, pe13, pp13, n1;
    float a0, a1;
    float pe1, pp1, pe3, pp3;
    float pw0, pw1;
    float* l2;                        // lds2 (t_j staging for e2f)
    unsigned aw, ae, ap;              // LDS byte addresses of w/e/p arrays
    int lane;
};

template <int G>
__device__ __forceinline__ void prefetch(Ctx& c) {
    constexpr int A = offA(G), B = G, S = G % 5;
    asm volatile(
        "ds_read2_b32 %[w], %[aw] offset0:%c[A] offset1:%c[B]\n\t"
        "ds_read2_b32 %[e], %[ae] offset0:%c[A] offset1:%c[B]\n\t"
        "ds_read2_b32 %[p], %[ap] offset0:%c[A] offset1:%c[B]\n\t"
        : [w] "+v"(c.bw[S]), [e] "+v"(c.be[S]), [p] "+v"(c.bp[S])
        : [aw] "v"(c.aw), [ae] "v"(c.ae), [ap] "v"(c.ap), [A] "i"(A), [B] "i"(B));
}

template <int G>
__device__ __forceinline__ void cstep(Ctx& c) {
    constexpr int rem = 198 - G;
    constexpr int K = 3 * (rem < 4 ? rem : 4);   // outstanding ds ops allowed
    constexpr int S = G % 5;
    if constexpr (G <= 6) {
        f2 t1, t2;
        asm volatile(
            "s_waitcnt lgkmcnt(%c[K])\n\t"
            "v_pk_fma_f32 %[t1], %[pe01], %[n1], %[be]\n\t"
            "v_pk_fma_f32 %[t2], %[pp01], %[n1], %[bp]\n\t"
            "v_pk_mul_f32 %[t1], %[t1], %[t1]\n\t"
            "v_pk_mul_f32 %[t2], %[t2], %[t2]\n\t"
            "v_pk_add_f32 %[t1], %[t1], %[t2]\n\t"
            "v_pk_mul_f32 %[tt], %[t1], %[bw]\n\t"
            "v_pk_fma_f32 %[t1], %[pe23], %[n1], %[be]\n\t"
            "v_pk_fma_f32 %[t2], %[pp23], %[n1], %[bp]\n\t"
            "v_pk_mul_f32 %[t1], %[t1], %[t1]\n\t"
            "v_pk_mul_f32 %[t2], %[t2], %[t2]\n\t"
            "v_pk_add_f32 %[t1], %[t1], %[t2]\n\t"
            "v_pk_mul_f32 %[t1], %[t1], %[bw]\n\t"
            "v_pk_add_f32 %[acc], %[acc], %[t1]\n\t"
            : [t1] "=&v"(t1), [t2] "=&v"(t2), [tt] "=&v"(c.tt),
              [acc] "+v"(c.acc23), [bw] "+v"(c.bw[S]), [be] "+v"(c.be[S]),
              [bp] "+v"(c.bp[S])
            : [pe01] "v"(c.pe01), [pp01] "v"(c.pp01), [pe23] "v"(c.pe23),
              [pp23] "v"(c.pp23), [n1] "v"(c.n1), [K] "i"(K));
        c.a1 = __fadd_rn(c.a1, c.tt.y);
        c.a0 = __fadd_rn(c.a0, (G < c.lane) ? c.tt.x : 0.0f);
    } else if constexpr (G <= 71) {
        f2 t1, t2;
        asm volatile(
            "s_waitcnt lgkmcnt(%c[K])\n\t"
            "v_pk_fma_f32 %[t1], %[pe23], %[n1], %[be]\n\t"
            "v_pk_fma_f32 %[t2], %[pp23], %[n1], %[bp]\n\t"
            "v_pk_mul_f32 %[t1], %[t1], %[t1]\n\t"
            "v_pk_mul_f32 %[t2], %[t2], %[t2]\n\t"
            "v_pk_add_f32 %[t1], %[t1], %[t2]\n\t"
            "v_pk_mul_f32 %[t1], %[t1], %[bw]\n\t"
            "v_pk_add_f32 %[acc], %[acc], %[t1]\n\t"
            : [t1] "=&v"(t1), [t2] "=&v"(t2), [acc] "+v"(c.acc23),
              [bw] "+v"(c.bw[S]), [be] "+v"(c.be[S]), [bp] "+v"(c.bp[S])
            : [pe23] "v"(c.pe23), [pp23] "v"(c.pp23), [n1] "v"(c.n1), [K] "i"(K));
        if constexpr (G == 7) {  // s1@7, unpredicated, np scalar order
            const float de = __fsub_rn(c.be[S].x, c.pe1);
            const float dp = __fsub_rn(c.bp[S].x, c.pp1);
            const float r2 = __fadd_rn(__fmul_rn(de, de), __fmul_rn(dp, dp));
            c.a1 = __fadd_rn(c.a1, __fmul_rn(r2, c.bw[S].x));
        }
    } else if constexpr (G <= 134) {
        if constexpr (G == 72) { c.accM.x = c.a1; c.accM.y = c.acc23.y; }
        // accM = [a1 (s1 pred, ii=G-72<lane), a3 (s3 unpred)]. cndmask in-asm
        // on clobbered v40 => one pk_add accumulates both halves.
        asm volatile(
            "s_waitcnt lgkmcnt(%c[K])\n\t"
            "v_pk_fma_f32 v[40:41], %[pe13], %[n1], %[be]\n\t"
            "v_pk_fma_f32 v[42:43], %[pp13], %[n1], %[bp]\n\t"
            "v_pk_mul_f32 v[40:41], v[40:41], v[40:41]\n\t"
            "v_pk_mul_f32 v[42:43], v[42:43], v[42:43]\n\t"
            "v_pk_add_f32 v[40:41], v[40:41], v[42:43]\n\t"
            "v_pk_mul_f32 v[40:41], v[40:41], %[bw]\n\t"
            "v_cmp_lt_u32 vcc, %c[II], %[lane]\n\t"
            "v_cndmask_b32 v40, 0, v40, vcc\n\t"
            "v_pk_add_f32 %[acc], %[acc], v[40:41]\n\t"
            : [acc] "+v"(c.accM), [bw] "+v"(c.bw[S]), [be] "+v"(c.be[S]),
              [bp] "+v"(c.bp[S])
            : [pe13] "v"(c.pe13), [pp13] "v"(c.pp13), [n1] "v"(c.n1),
              [K] "i"(K), [II] "i"(G - 72), [lane] "v"(c.lane)
            : "v40", "v41", "v42", "v43", "vcc");
    } else if constexpr (G == 135) {
        asm volatile("s_waitcnt lgkmcnt(%c[K])"
                     : [bw] "+v"(c.bw[S]), [be] "+v"(c.be[S]), [bp] "+v"(c.bp[S])
                     : [K] "i"(K));
        const float de = __fsub_rn(c.be[S].x, c.pe3);
        const float dp = __fsub_rn(c.bp[S].x, c.pp3);
        const float r2 = __fadd_rn(__fmul_rn(de, de), __fmul_rn(dp, dp));
        c.accM.y = __fadd_rn(c.accM.y, __fmul_rn(r2, c.bw[S].x));
    } else {
        if constexpr (G == 136) { c.accY.x = c.acc23.x; c.accY.y = c.accM.y; }
        constexpr unsigned sh = G - 135;  // v+1, 1..63; active lanes: lane > v
        constexpr unsigned lm = sh < 32 ? (0xFFFFFFFFu << sh) : 0u;
        constexpr unsigned hm = sh < 32 ? 0xFFFFFFFFu : (0xFFFFFFFFu << (sh - 32));
        f2 t1, t2;
        asm volatile(
            "s_waitcnt lgkmcnt(%c[K])\n\t"
            "s_mov_b32 exec_lo, %c[LM]\n\t"
            "s_mov_b32 exec_hi, %c[HM]\n\t"
            "v_pk_fma_f32 %[t1], %[pe23], %[n1], %[be]\n\t"
            "v_pk_fma_f32 %[t2], %[pp23], %[n1], %[bp]\n\t"
            "v_pk_mul_f32 %[t1], %[t1], %[t1]\n\t"
            "v_pk_mul_f32 %[t2], %[t2], %[t2]\n\t"
            "v_pk_add_f32 %[t1], %[t1], %[t2]\n\t"
            "v_pk_mul_f32 %[t1], %[t1], %[bw]\n\t"
            "v_pk_add_f32 %[acc], %[acc], %[t1]\n\t"
            "s_mov_b64 exec, -1\n\t"
            : [t1] "=&v"(t1), [t2] "=&v"(t2), [acc] "+v"(c.accY),
              [bw] "+v"(c.bw[S]), [be] "+v"(c.be[S]), [bp] "+v"(c.bp[S])
            : [pe23] "v"(c.pe23), [pp23] "v"(c.pp23), [n1] "v"(c.n1),
              [K] "i"(K), [LM] "i"(lm), [HM] "i"(hm));
    }
}

template <int G>
__device__ __forceinline__ void run(Ctx& c) {
    if constexpr (G <= 198) {
        cstep<G>(c);
        // t_j staging hooks (lgkm-safe: extra outstanding write only makes
        // later counted waits more conservative).
        if constexpr (G == 6) {   // t0 final (s0 has only i=0..6)
            c.l2[c.lane] = __fmul_rn(c.pw0, c.a0);  // lanes>=8 garbage, overwritten
        }
        if constexpr (G == 134) { // t1 final (s1 pred ends at i=134-64=70)
            c.l2[8 + c.lane] = __fmul_rn(c.pw1, c.accM.x);
        }
        if constexpr (G + 5 <= 198) prefetch<G + 5>(c);
        run<G + 1>(c);
    }
}

__global__ __launch_bounds__(64) void jet_ecf_kernel(const float* __restrict__ x,
                                                     float* __restrict__ out,
                                                     int njet) {
#pragma clang fp contract(off)
    const int jet = blockIdx.x;
    if (jet >= njet) return;
    const int lane = threadIdx.x;
    const float* xj = x + (size_t)jet * NPART * 3;

    __shared__ float lds[600];                  // SoA: w, e, p
    __shared__ __align__(16) float lds2[200];   // t_j staging for e2f

    // Slot register loads: slot0: j=lane (lanes 0..7), slot1: j=8+lane,
    // slot2: j=72+lane, slot3: j=136+lane. Dummy lanes zero-padded.
    float pw[4], pea[4], ppa[4];
    {
        const int base[4] = {0, 8, 72, 136};
        #pragma unroll
        for (int k = 0; k < 4; ++k) {
            const int p = base[k] + lane;
            const bool valid = (k > 0) || (lane < 8);
            if (valid) {
                pw[k] = xj[p * 3 + 0];
                pea[k] = xj[p * 3 + 1];
                ppa[k] = xj[p * 3 + 2];
            } else {
                pw[k] = 0.0f; pea[k] = 0.0f; ppa[k] = 0.0f;
            }
        }
    }

    // LDS staging of i-side values.
    #pragma unroll
    for (int r = 0; r < 4; ++r) {
        const int i = lane + (r << 6);
        if (i < NPART) {
            lds[i]       = xj[3 * i + 0];
            lds[200 + i] = xj[3 * i + 1];
            lds[400 + i] = xj[3 * i + 2];
        }
    }

    // ---- Phase A: exact fp64 moments (ecf1, ecf3). fp64 is an oracle here;
    // explicit fma() restructure (contract(off) otherwise de-fuses): 15 ops/k.
    double S = 0, Sa = 0, Se = 0, Sp = 0, Saa = 0;
    double Sae = 0, Sap = 0, See = 0, Spp = 0, Sep = 0;
    #pragma unroll
    for (int k = 0; k < 4; ++k) {
        const double w = (double)pw[k];
        const double e = (double)pea[k];
        const double f = (double)ppa[k];
        const double a = fma(f, f, e * e);
        const double wa = w * a, we = w * e, wf = w * f;
        S += w; Sa += wa; Se += we; Sp += wf;
        Saa = fma(wa, a, Saa);
        Sae = fma(wa, e, Sae);
        Sap = fma(wa, f, Sap);
        See = fma(we, e, See);
        Sep = fma(we, f, Sep);
        Spp = fma(wf, f, Spp);
    }
    #pragma unroll
    for (int off = 32; off > 0; off >>= 1) {
        S   += __shfl_down(S,   off, 64);
        Sa  += __shfl_down(Sa,  off, 64);
        Se  += __shfl_down(Se,  off, 64);
        Sp  += __shfl_down(Sp,  off, 64);
        Saa += __shfl_down(Saa, off, 64);
        Sae += __shfl_down(Sae, off, 64);
        Sap += __shfl_down(Sap, off, 64);
        See += __shfl_down(See, off, 64);
        Spp += __shfl_down(Spp, off, 64);
        Sep += __shfl_down(Sep, off, 64);
    }

    __syncthreads();
    asm volatile("" ::: "memory");  // keep LDS stores (asm reads them)
    // Pin Phase A results; hard boundary so no Phase A lgkm ops drift into
    // the counted Phase B region.
    asm volatile("" :: "v"(S), "v"(Sa), "v"(Se), "v"(Sp), "v"(Saa),
                       "v"(Sae), "v"(Sap), "v"(See), "v"(Spp), "v"(Sep));
    __builtin_amdgcn_sched_barrier(0);
    asm volatile("s_waitcnt lgkmcnt(0)" ::: );

    // ---- Phase B: np-order fp32 column sums, packed 2-wide.
    Ctx c;
    c.lane = lane;
    c.aw = (unsigned)(uintptr_t)&lds[0];
    c.ae = (unsigned)(uintptr_t)&lds[200];
    c.ap = (unsigned)(uintptr_t)&lds[400];
    c.l2 = lds2;
    c.pw0 = pw[0]; c.pw1 = pw[1];
    c.n1.x = -1.0f; c.n1.y = -1.0f;
    c.pe01.x = pea[0]; c.pe01.y = pea[1];
    c.pp01.x = ppa[0]; c.pp01.y = ppa[1];
    c.pe23.x = pea[2]; c.pe23.y = pea[3];
    c.pp23.x = ppa[2]; c.pp23.y = ppa[3];
    c.pe13.x = pea[1]; c.pe13.y = pea[3];
    c.pp13.x = ppa[1]; c.pp13.y = ppa[3];
    c.pe1 = pea[1]; c.pp1 = ppa[1]; c.pe3 = pea[3]; c.pp3 = ppa[3];
    c.acc23.x = 0.0f; c.acc23.y = 0.0f;
    c.accY.x = 0.0f;  c.accY.y = 0.0f;
    c.accM.x = 0.0f;  c.accM.y = 0.0f;
    c.tt.x = 0.0f;    c.tt.y = 0.0f;
    c.a0 = c.a1 = 0.0f;
    #pragma unroll
    for (int k = 0; k < 5; ++k) {
        c.bw[k].x = 0.0f; c.bw[k].y = 0.0f;
        c.be[k].x = 0.0f; c.be[k].y = 0.0f;
        c.bp[k].x = 0.0f; c.bp[k].y = 0.0f;
    }

    prefetch<0>(c); prefetch<1>(c); prefetch<2>(c); prefetch<3>(c); prefetch<4>(c);
    run<0>(c);

    // Final t stores: t2 = pw2*s2, t3 = pw3*s3 (finals in accY).
    lds2[72 + lane]  = __fmul_rn(pw[2], c.accY.x);
    lds2[136 + lane] = __fmul_rn(pw[3], c.accY.y);

    // Explicit fence: all lds2 writes (hooks + finals, cross-lane) complete
    // before the float4 read-back. Same-wave DS retires in order, but make it
    // explicit rather than assumed.
    asm volatile("s_waitcnt lgkmcnt(0)" ::: "memory");

    // ecf2 = sum_j fl(pt_j*s_j), sequential ascending j — identical values
    // and order to the readlane chain; 50x ds_read_b128 + 200 adds.
    float e2f = 0.0f;
    {
        const float4* lt = reinterpret_cast<const float4*>(lds2);
        #pragma unroll
        for (int q = 0; q < 50; ++q) {
            const float4 v = lt[q];
            e2f = __fadd_rn(e2f, v.x);
            e2f = __fadd_rn(e2f, v.y);
            e2f = __fadd_rn(e2f, v.z);
            e2f = __fadd_rn(e2f, v.w);
        }
    }

    if (lane == 0) {
        const double A[4][4] = {
            {  Saa,        Sa,       -2.0 * Sae, -2.0 * Sap },
            {  Sa,         S,        -2.0 * Se,  -2.0 * Sp  },
            { -2.0 * Sae, -2.0 * Se,  4.0 * See,  4.0 * Sep },
            { -2.0 * Sap, -2.0 * Sp,  4.0 * Sep,  4.0 * Spp }
        };
        const double B[4][4] = {
            { Sa,  S,  -2.0 * Se,  -2.0 * Sp  },
            { Saa, Sa, -2.0 * Sae, -2.0 * Sap },
            { Sae, Se, -2.0 * See, -2.0 * Sep },
            { Sap, Sp, -2.0 * Sep, -2.0 * Spp }
        };
        const double C[4][4] = {
            { S,  Sa,  Se,  Sp  },
            { Sa, Saa, Sae, Sap },
            { Se, Sae, See, Sep },
            { Sp, Sap, Sep, Spp }
        };
        double T = 0.0;
        #pragma unroll
        for (int b = 0; b < 4; ++b) {
            #pragma unroll
            for (int g = 0; g < 4; ++g) {
                double ab = 0.0;
                #pragma unroll
                for (int al = 0; al < 4; ++al) ab += A[al][b] * B[al][g];
                T += ab * C[b][g];
            }
        }
        const double ecf1 = S;
        const double ecf2 = (double)e2f;
        const double ecf3 = T * (1.0 / 6.0);
        const double d2 = ecf3 * ecf1 * ecf1 * ecf1 / (ecf2 * ecf2 * ecf2 + 1e-7);
        float4 o = make_float4((float)ecf1, (float)ecf2, (float)ecf3, (float)d2);
        *reinterpret_cast<float4*>(out + (size_t)jet * 4) = o;
    }
}

extern "C" void kernel_launch(void* const* d_in, const int* in_sizes, int n_in,
                              void* d_out, int out_size, void* d_ws, size_t ws_size,
                              hipStream_t stream) {
    const float* x = (const float*)d_in[0];
    float* out = (float*)d_out;
    const int njet = in_sizes[0] / (NPART * 3);
    jet_ecf_kernel<<<njet, 64, 0, stream>>>(x, out, njet);
}

// Round 4
// 68.932 us; speedup vs baseline: 1.0520x; 1.0112x over previous
//
#include <hip/hip_runtime.h>

// JetECF, beta=2. Established facts (R0-R11):
//  - Output fp32; harness bf16-rounds both sides. ecf2 must replicate numpy's
//    fp32 op order BIT-EXACTLY (immutable): per column j, sequential ascending
//    i, single fp32 acc, ops fl(fl(fl(de^2)+fl(dp^2))*pt_i); final sum over j
//    ascending, single fp32 acc. ecf1/ecf3 via exact fp64 rank-4 identity
//    (oracle: any fp64-accurate variant OK).
//  - Harness floor ~64.7us; R11 kernel ~5.0us. v_pk_*_f32 = 2-cyc wave64.
//    Phase B at structural floor: 205 pk-groups (min 206 half-steps), 4-slot
//    partition Sigma-max = 412 provably minimal, 7 fl-ops/pair immutable.
//  - Remaining cost = serial latency chains: shfl-reduction (~960cy) and
//    e2f 200-add chain (~800cy), previously sequential.
//
// R12 change: move Phase A (f64 moments + 6-level shfl reduction) to AFTER
// Phase B and interleave the reduction levels into the e2f quad loop — the
// two independent chains (different pipes) now overlap: max() not sum().
// Also: drop vestigial __syncthreads (block = 1 wave); moments no longer
// live across Phase B (VGPR pressure down). No ecf2 fl-op changes.

constexpr int NPART = 200;
typedef float f2 __attribute__((ext_vector_type(2)));

constexpr int offA(int g) {
    return (g < 72) ? g : (g == 135 ? 135 : g - 64);
}

struct Ctx {
    f2 bw[5], be[5], bp[5];           // prefetch buffers (rotating, idx G%5)
    f2 acc23, accY, accM, tt;
    f2 pe01, pp01, pe23, pp23, pe13, pp13, n1;
    float a0, a1;
    float pe1, pp1, pe3, pp3;
    float pw0, pw1;
    float* l2;                        // lds2 (t_j staging for e2f)
    unsigned aw, ae, ap;              // LDS byte addresses of w/e/p arrays
    int lane;
};

template <int G>
__device__ __forceinline__ void prefetch(Ctx& c) {
    constexpr int A = offA(G), B = G, S = G % 5;
    asm volatile(
        "ds_read2_b32 %[w], %[aw] offset0:%c[A] offset1:%c[B]\n\t"
        "ds_read2_b32 %[e], %[ae] offset0:%c[A] offset1:%c[B]\n\t"
        "ds_read2_b32 %[p], %[ap] offset0:%c[A] offset1:%c[B]\n\t"
        : [w] "+v"(c.bw[S]), [e] "+v"(c.be[S]), [p] "+v"(c.bp[S])
        : [aw] "v"(c.aw), [ae] "v"(c.ae), [ap] "v"(c.ap), [A] "i"(A), [B] "i"(B));
}

template <int G>
__device__ __forceinline__ void cstep(Ctx& c) {
    constexpr int rem = 198 - G;
    constexpr int K = 3 * (rem < 4 ? rem : 4);   // outstanding ds ops allowed
    constexpr int S = G % 5;
    if constexpr (G <= 6) {
        f2 t1, t2;
        asm volatile(
            "s_waitcnt lgkmcnt(%c[K])\n\t"
            "v_pk_fma_f32 %[t1], %[pe01], %[n1], %[be]\n\t"
            "v_pk_fma_f32 %[t2], %[pp01], %[n1], %[bp]\n\t"
            "v_pk_mul_f32 %[t1], %[t1], %[t1]\n\t"
            "v_pk_mul_f32 %[t2], %[t2], %[t2]\n\t"
            "v_pk_add_f32 %[t1], %[t1], %[t2]\n\t"
            "v_pk_mul_f32 %[tt], %[t1], %[bw]\n\t"
            "v_pk_fma_f32 %[t1], %[pe23], %[n1], %[be]\n\t"
            "v_pk_fma_f32 %[t2], %[pp23], %[n1], %[bp]\n\t"
            "v_pk_mul_f32 %[t1], %[t1], %[t1]\n\t"
            "v_pk_mul_f32 %[t2], %[t2], %[t2]\n\t"
            "v_pk_add_f32 %[t1], %[t1], %[t2]\n\t"
            "v_pk_mul_f32 %[t1], %[t1], %[bw]\n\t"
            "v_pk_add_f32 %[acc], %[acc], %[t1]\n\t"
            : [t1] "=&v"(t1), [t2] "=&v"(t2), [tt] "=&v"(c.tt),
              [acc] "+v"(c.acc23), [bw] "+v"(c.bw[S]), [be] "+v"(c.be[S]),
              [bp] "+v"(c.bp[S])
            : [pe01] "v"(c.pe01), [pp01] "v"(c.pp01), [pe23] "v"(c.pe23),
              [pp23] "v"(c.pp23), [n1] "v"(c.n1), [K] "i"(K));
        c.a1 = __fadd_rn(c.a1, c.tt.y);
        c.a0 = __fadd_rn(c.a0, (G < c.lane) ? c.tt.x : 0.0f);
    } else if constexpr (G <= 71) {
        f2 t1, t2;
        asm volatile(
            "s_waitcnt lgkmcnt(%c[K])\n\t"
            "v_pk_fma_f32 %[t1], %[pe23], %[n1], %[be]\n\t"
            "v_pk_fma_f32 %[t2], %[pp23], %[n1], %[bp]\n\t"
            "v_pk_mul_f32 %[t1], %[t1], %[t1]\n\t"
            "v_pk_mul_f32 %[t2], %[t2], %[t2]\n\t"
            "v_pk_add_f32 %[t1], %[t1], %[t2]\n\t"
            "v_pk_mul_f32 %[t1], %[t1], %[bw]\n\t"
            "v_pk_add_f32 %[acc], %[acc], %[t1]\n\t"
            : [t1] "=&v"(t1), [t2] "=&v"(t2), [acc] "+v"(c.acc23),
              [bw] "+v"(c.bw[S]), [be] "+v"(c.be[S]), [bp] "+v"(c.bp[S])
            : [pe23] "v"(c.pe23), [pp23] "v"(c.pp23), [n1] "v"(c.n1), [K] "i"(K));
        if constexpr (G == 7) {  // s1@7, unpredicated, np scalar order
            const float de = __fsub_rn(c.be[S].x, c.pe1);
            const float dp = __fsub_rn(c.bp[S].x, c.pp1);
            const float r2 = __fadd_rn(__fmul_rn(de, de), __fmul_rn(dp, dp));
            c.a1 = __fadd_rn(c.a1, __fmul_rn(r2, c.bw[S].x));
        }
    } else if constexpr (G <= 134) {
        if constexpr (G == 72) { c.accM.x = c.a1; c.accM.y = c.acc23.y; }
        // accM = [a1 (s1 pred, ii=G-72<lane), a3 (s3 unpred)]. cndmask in-asm
        // on clobbered v40 => one pk_add accumulates both halves.
        asm volatile(
            "s_waitcnt lgkmcnt(%c[K])\n\t"
            "v_pk_fma_f32 v[40:41], %[pe13], %[n1], %[be]\n\t"
            "v_pk_fma_f32 v[42:43], %[pp13], %[n1], %[bp]\n\t"
            "v_pk_mul_f32 v[40:41], v[40:41], v[40:41]\n\t"
            "v_pk_mul_f32 v[42:43], v[42:43], v[42:43]\n\t"
            "v_pk_add_f32 v[40:41], v[40:41], v[42:43]\n\t"
            "v_pk_mul_f32 v[40:41], v[40:41], %[bw]\n\t"
            "v_cmp_lt_u32 vcc, %c[II], %[lane]\n\t"
            "v_cndmask_b32 v40, 0, v40, vcc\n\t"
            "v_pk_add_f32 %[acc], %[acc], v[40:41]\n\t"
            : [acc] "+v"(c.accM), [bw] "+v"(c.bw[S]), [be] "+v"(c.be[S]),
              [bp] "+v"(c.bp[S])
            : [pe13] "v"(c.pe13), [pp13] "v"(c.pp13), [n1] "v"(c.n1),
              [K] "i"(K), [II] "i"(G - 72), [lane] "v"(c.lane)
            : "v40", "v41", "v42", "v43", "vcc");
    } else if constexpr (G == 135) {
        asm volatile("s_waitcnt lgkmcnt(%c[K])"
                     : [bw] "+v"(c.bw[S]), [be] "+v"(c.be[S]), [bp] "+v"(c.bp[S])
                     : [K] "i"(K));
        const float de = __fsub_rn(c.be[S].x, c.pe3);
        const float dp = __fsub_rn(c.bp[S].x, c.pp3);
        const float r2 = __fadd_rn(__fmul_rn(de, de), __fmul_rn(dp, dp));
        c.accM.y = __fadd_rn(c.accM.y, __fmul_rn(r2, c.bw[S].x));
    } else {
        if constexpr (G == 136) { c.accY.x = c.acc23.x; c.accY.y = c.accM.y; }
        constexpr unsigned sh = G - 135;  // v+1, 1..63; active lanes: lane > v
        constexpr unsigned lm = sh < 32 ? (0xFFFFFFFFu << sh) : 0u;
        constexpr unsigned hm = sh < 32 ? 0xFFFFFFFFu : (0xFFFFFFFFu << (sh - 32));
        f2 t1, t2;
        asm volatile(
            "s_waitcnt lgkmcnt(%c[K])\n\t"
            "s_mov_b32 exec_lo, %c[LM]\n\t"
            "s_mov_b32 exec_hi, %c[HM]\n\t"
            "v_pk_fma_f32 %[t1], %[pe23], %[n1], %[be]\n\t"
            "v_pk_fma_f32 %[t2], %[pp23], %[n1], %[bp]\n\t"
            "v_pk_mul_f32 %[t1], %[t1], %[t1]\n\t"
            "v_pk_mul_f32 %[t2], %[t2], %[t2]\n\t"
            "v_pk_add_f32 %[t1], %[t1], %[t2]\n\t"
            "v_pk_mul_f32 %[t1], %[t1], %[bw]\n\t"
            "v_pk_add_f32 %[acc], %[acc], %[t1]\n\t"
            "s_mov_b64 exec, -1\n\t"
            : [t1] "=&v"(t1), [t2] "=&v"(t2), [acc] "+v"(c.accY),
              [bw] "+v"(c.bw[S]), [be] "+v"(c.be[S]), [bp] "+v"(c.bp[S])
            : [pe23] "v"(c.pe23), [pp23] "v"(c.pp23), [n1] "v"(c.n1),
              [K] "i"(K), [LM] "i"(lm), [HM] "i"(hm));
    }
}

template <int G>
__device__ __forceinline__ void run(Ctx& c) {
    if constexpr (G <= 198) {
        cstep<G>(c);
        // t_j staging hooks (lgkm-safe: extra outstanding write only makes
        // later counted waits more conservative).
        if constexpr (G == 6) {   // t0 final (s0 has only i=0..6)
            c.l2[c.lane] = __fmul_rn(c.pw0, c.a0);  // lanes>=8 garbage, overwritten
        }
        if constexpr (G == 134) { // t1 final (s1 pred ends at i=134-64=70)
            c.l2[8 + c.lane] = __fmul_rn(c.pw1, c.accM.x);
        }
        if constexpr (G + 5 <= 198) prefetch<G + 5>(c);
        run<G + 1>(c);
    }
}

__global__ __launch_bounds__(64) void jet_ecf_kernel(const float* __restrict__ x,
                                                     float* __restrict__ out,
                                                     int njet) {
#pragma clang fp contract(off)
    const int jet = blockIdx.x;
    if (jet >= njet) return;
    const int lane = threadIdx.x;
    const float* xj = x + (size_t)jet * NPART * 3;

    __shared__ float lds[600];                  // SoA: w, e, p
    __shared__ __align__(16) float lds2[200];   // t_j staging for e2f

    // Slot register loads: slot0: j=lane (lanes 0..7), slot1: j=8+lane,
    // slot2: j=72+lane, slot3: j=136+lane. Dummy lanes zero-padded.
    float pw[4], pea[4], ppa[4];
    {
        const int base[4] = {0, 8, 72, 136};
        #pragma unroll
        for (int k = 0; k < 4; ++k) {
            const int p = base[k] + lane;
            const bool valid = (k > 0) || (lane < 8);
            if (valid) {
                pw[k] = xj[p * 3 + 0];
                pea[k] = xj[p * 3 + 1];
                ppa[k] = xj[p * 3 + 2];
            } else {
                pw[k] = 0.0f; pea[k] = 0.0f; ppa[k] = 0.0f;
            }
        }
    }

    // LDS staging of i-side values.
    #pragma unroll
    for (int r = 0; r < 4; ++r) {
        const int i = lane + (r << 6);
        if (i < NPART) {
            lds[i]       = xj[3 * i + 0];
            lds[200 + i] = xj[3 * i + 1];
            lds[400 + i] = xj[3 * i + 2];
        }
    }

    // Pin staging stores before Phase B's asm reads them (block = 1 wave, so
    // no barrier needed — just an explicit drain + compiler memory fence).
    asm volatile("" ::: "memory");
    __builtin_amdgcn_sched_barrier(0);
    asm volatile("s_waitcnt lgkmcnt(0)" ::: "memory");

    // ---- Phase B: np-order fp32 column sums, packed 2-wide.
    Ctx c;
    c.lane = lane;
    c.aw = (unsigned)(uintptr_t)&lds[0];
    c.ae = (unsigned)(uintptr_t)&lds[200];
    c.ap = (unsigned)(uintptr_t)&lds[400];
    c.l2 = lds2;
    c.pw0 = pw[0]; c.pw1 = pw[1];
    c.n1.x = -1.0f; c.n1.y = -1.0f;
    c.pe01.x = pea[0]; c.pe01.y = pea[1];
    c.pp01.x = ppa[0]; c.pp01.y = ppa[1];
    c.pe23.x = pea[2]; c.pe23.y = pea[3];
    c.pp23.x = ppa[2]; c.pp23.y = ppa[3];
    c.pe13.x = pea[1]; c.pe13.y = pea[3];
    c.pp13.x = ppa[1]; c.pp13.y = ppa[3];
    c.pe1 = pea[1]; c.pp1 = ppa[1]; c.pe3 = pea[3]; c.pp3 = ppa[3];
    c.acc23.x = 0.0f; c.acc23.y = 0.0f;
    c.accY.x = 0.0f;  c.accY.y = 0.0f;
    c.accM.x = 0.0f;  c.accM.y = 0.0f;
    c.tt.x = 0.0f;    c.tt.y = 0.0f;
    c.a0 = c.a1 = 0.0f;
    #pragma unroll
    for (int k = 0; k < 5; ++k) {
        c.bw[k].x = 0.0f; c.bw[k].y = 0.0f;
        c.be[k].x = 0.0f; c.be[k].y = 0.0f;
        c.bp[k].x = 0.0f; c.bp[k].y = 0.0f;
    }

    prefetch<0>(c); prefetch<1>(c); prefetch<2>(c); prefetch<3>(c); prefetch<4>(c);
    run<0>(c);

    // Final t stores: t2 = pw2*s2, t3 = pw3*s3 (finals in accY).
    lds2[72 + lane]  = __fmul_rn(pw[2], c.accY.x);
    lds2[136 + lane] = __fmul_rn(pw[3], c.accY.y);

    // ---- Phase A (moved post-B): exact fp64 moments. fp64 oracle; explicit
    // fma() since contract(off). Pure VALU — issues while lds2 writes drain.
    double S = 0, Sa = 0, Se = 0, Sp = 0, Saa = 0;
    double Sae = 0, Sap = 0, See = 0, Spp = 0, Sep = 0;
    #pragma unroll
    for (int k = 0; k < 4; ++k) {
        const double w = (double)pw[k];
        const double e = (double)pea[k];
        const double f = (double)ppa[k];
        const double a = fma(f, f, e * e);
        const double wa = w * a, we = w * e, wf = w * f;
        S += w; Sa += wa; Se += we; Sp += wf;
        Saa = fma(wa, a, Saa);
        Sae = fma(wa, e, Sae);
        Sap = fma(wa, f, Sap);
        See = fma(we, e, See);
        Sep = fma(we, f, Sep);
        Spp = fma(wf, f, Spp);
    }

    // Fence: all lds2 writes (hooks + finals) complete before float4 reads.
    asm volatile("s_waitcnt lgkmcnt(0)" ::: "memory");

    // ecf2 = sum_j fl(pt_j*s_j), sequential ascending j — identical values
    // and order to before. The 200-add dependent chain is interleaved with
    // the 6-level shfl reduction (independent chains, different pipes):
    // wall = max(chains) instead of sum.
    float e2f = 0.0f;
    const float4* lt = reinterpret_cast<const float4*>(lds2);
#define QUAD(Q)                                                               \
    {                                                                         \
        const float4 v = lt[Q];                                               \
        e2f = __fadd_rn(e2f, v.x);                                            \
        e2f = __fadd_rn(e2f, v.y);                                            \
        e2f = __fadd_rn(e2f, v.z);                                            \
        e2f = __fadd_rn(e2f, v.w);                                            \
    }
#define QUADS8(B)                                                             \
    QUAD(B) QUAD(B + 1) QUAD(B + 2) QUAD(B + 3)                               \
    QUAD(B + 4) QUAD(B + 5) QUAD(B + 6) QUAD(B + 7)
#define RED(OFF)                                                              \
    S   += __shfl_down(S,   OFF, 64);                                         \
    Sa  += __shfl_down(Sa,  OFF, 64);                                         \
    Se  += __shfl_down(Se,  OFF, 64);                                         \
    Sp  += __shfl_down(Sp,  OFF, 64);                                         \
    Saa += __shfl_down(Saa, OFF, 64);                                         \
    Sae += __shfl_down(Sae, OFF, 64);                                         \
    Sap += __shfl_down(Sap, OFF, 64);                                         \
    See += __shfl_down(See, OFF, 64);                                         \
    Spp += __shfl_down(Spp, OFF, 64);                                         \
    Sep += __shfl_down(Sep, OFF, 64);

    QUADS8(0)   RED(32)
    QUADS8(8)   RED(16)
    QUADS8(16)  RED(8)
    QUADS8(24)  RED(4)
    QUADS8(32)  RED(2)
    QUADS8(40)  RED(1)
    QUAD(48) QUAD(49)
#undef QUAD
#undef QUADS8
#undef RED

    if (lane == 0) {
        const double A[4][4] = {
            {  Saa,        Sa,       -2.0 * Sae, -2.0 * Sap },
            {  Sa,         S,        -2.0 * Se,  -2.0 * Sp  },
            { -2.0 * Sae, -2.0 * Se,  4.0 * See,  4.0 * Sep },
            { -2.0 * Sap, -2.0 * Sp,  4.0 * Sep,  4.0 * Spp }
        };
        const double B[4][4] = {
            { Sa,  S,  -2.0 * Se,  -2.0 * Sp  },
            { Saa, Sa, -2.0 * Sae, -2.0 * Sap },
            { Sae, Se, -2.0 * See, -2.0 * Sep },
            { Sap, Sp, -2.0 * Sep, -2.0 * Spp }
        };
        const double C[4][4] = {
            { S,  Sa,  Se,  Sp  },
            { Sa, Saa, Sae, Sap },
            { Se, Sae, See, Sep },
            { Sp, Sap, Sep, Spp }
        };
        double T = 0.0;
        #pragma unroll
        for (int b = 0; b < 4; ++b) {
            #pragma unroll
            for (int g = 0; g < 4; ++g) {
                double ab = 0.0;
                #pragma unroll
                for (int al = 0; al < 4; ++al) ab += A[al][b] * B[al][g];
                T += ab * C[b][g];
            }
        }
        const double ecf1 = S;
        const double ecf2 = (double)e2f;
        const double ecf3 = T * (1.0 / 6.0);
        const double d2 = ecf3 * ecf1 * ecf1 * ecf1 / (ecf2 * ecf2 * ecf2 + 1e-7);
        float4 o = make_float4((float)ecf1, (float)ecf2, (float)ecf3, (float)d2);
        *reinterpret_cast<float4*>(out + (size_t)jet * 4) = o;
    }
}

extern "C" void kernel_launch(void* const* d_in, const int* in_sizes, int n_in,
                              void* d_out, int out_size, void* d_ws, size_t ws_size,
                              hipStream_t stream) {
    const float* x = (const float*)d_in[0];
    float* out = (float*)d_out;
    const int njet = in_sizes[0] / (NPART * 3);
    jet_ecf_kernel<<<njet, 64, 0, stream>>>(x, out, njet);
}

// Round 5
// 68.139 us; speedup vs baseline: 1.0643x; 1.0116x over previous
//
#include <hip/hip_runtime.h>

// JetECF, beta=2. Established facts (R0-R12):
//  - Output fp32; harness bf16-rounds both sides. ecf2 must replicate numpy's
//    fp32 op order BIT-EXACTLY (immutable): per column j, sequential ascending
//    i, single fp32 acc, ops fl(fl(fl(de^2)+fl(dp^2))*pt_i); final sum over j
//    ascending, single fp32 acc. ecf1/ecf3 via exact fp64 rank-4 identity
//    (oracle: any fp64-accurate variant OK).
//  - Harness floor ~64.7us; R12 kernel ~4.2us. v_pk_*_f32 = 2-cyc wave64.
//    Phase B at structural floor: 205 pk-pairs (min 206 half-steps), 4-slot
//    partition Sigma-max = 412 provably minimal, 7 fl-ops/pair immutable.
//  - R12 overlapped the shfl-reduction with the e2f add chain (post-B Phase A).
//
// R13 changes (shave non-structural VALU):
//  1. Seg C (G=72..134): predicate ii<lane has a COMPILE-TIME lane mask
//     (lane >= G-71). Load it into vcc via 2x s_mov_b32 (SALU, hidden under
//     the other wave's VALU) instead of v_cmp (VALU): 9->8 VALU/step, -63/wave.
//  2. Epilogue: A's rows are signed perms of B's rows (A0=B1, A1=B0,
//     A2=-2*B2, A3=-2*B3) => ab[b][g] symmetric = R1bR0g+R0bR1g-2R2bR2g
//     -2R3bR3g. 10 cells x 4 fma + (D+2U) combine: ~80 f64 issues vs ~110.
//     fp64 oracle — reordering legal (verified symbolically vs original).

constexpr int NPART = 200;
typedef float f2 __attribute__((ext_vector_type(2)));

constexpr int offA(int g) {
    return (g < 72) ? g : (g == 135 ? 135 : g - 64);
}

struct Ctx {
    f2 bw[5], be[5], bp[5];           // prefetch buffers (rotating, idx G%5)
    f2 acc23, accY, accM, tt;
    f2 pe01, pp01, pe23, pp23, pe13, pp13, n1;
    float a0, a1;
    float pe1, pp1, pe3, pp3;
    float pw0, pw1;
    float* l2;                        // lds2 (t_j staging for e2f)
    unsigned aw, ae, ap;              // LDS byte addresses of w/e/p arrays
    int lane;
};

template <int G>
__device__ __forceinline__ void prefetch(Ctx& c) {
    constexpr int A = offA(G), B = G, S = G % 5;
    asm volatile(
        "ds_read2_b32 %[w], %[aw] offset0:%c[A] offset1:%c[B]\n\t"
        "ds_read2_b32 %[e], %[ae] offset0:%c[A] offset1:%c[B]\n\t"
        "ds_read2_b32 %[p], %[ap] offset0:%c[A] offset1:%c[B]\n\t"
        : [w] "+v"(c.bw[S]), [e] "+v"(c.be[S]), [p] "+v"(c.bp[S])
        : [aw] "v"(c.aw), [ae] "v"(c.ae), [ap] "v"(c.ap), [A] "i"(A), [B] "i"(B));
}

template <int G>
__device__ __forceinline__ void cstep(Ctx& c) {
    constexpr int rem = 198 - G;
    constexpr int K = 3 * (rem < 4 ? rem : 4);   // outstanding ds ops allowed
    constexpr int S = G % 5;
    if constexpr (G <= 6) {
        f2 t1, t2;
        asm volatile(
            "s_waitcnt lgkmcnt(%c[K])\n\t"
            "v_pk_fma_f32 %[t1], %[pe01], %[n1], %[be]\n\t"
            "v_pk_fma_f32 %[t2], %[pp01], %[n1], %[bp]\n\t"
            "v_pk_mul_f32 %[t1], %[t1], %[t1]\n\t"
            "v_pk_mul_f32 %[t2], %[t2], %[t2]\n\t"
            "v_pk_add_f32 %[t1], %[t1], %[t2]\n\t"
            "v_pk_mul_f32 %[tt], %[t1], %[bw]\n\t"
            "v_pk_fma_f32 %[t1], %[pe23], %[n1], %[be]\n\t"
            "v_pk_fma_f32 %[t2], %[pp23], %[n1], %[bp]\n\t"
            "v_pk_mul_f32 %[t1], %[t1], %[t1]\n\t"
            "v_pk_mul_f32 %[t2], %[t2], %[t2]\n\t"
            "v_pk_add_f32 %[t1], %[t1], %[t2]\n\t"
            "v_pk_mul_f32 %[t1], %[t1], %[bw]\n\t"
            "v_pk_add_f32 %[acc], %[acc], %[t1]\n\t"
            : [t1] "=&v"(t1), [t2] "=&v"(t2), [tt] "=&v"(c.tt),
              [acc] "+v"(c.acc23), [bw] "+v"(c.bw[S]), [be] "+v"(c.be[S]),
              [bp] "+v"(c.bp[S])
            : [pe01] "v"(c.pe01), [pp01] "v"(c.pp01), [pe23] "v"(c.pe23),
              [pp23] "v"(c.pp23), [n1] "v"(c.n1), [K] "i"(K));
        c.a1 = __fadd_rn(c.a1, c.tt.y);
        c.a0 = __fadd_rn(c.a0, (G < c.lane) ? c.tt.x : 0.0f);
    } else if constexpr (G <= 71) {
        f2 t1, t2;
        asm volatile(
            "s_waitcnt lgkmcnt(%c[K])\n\t"
            "v_pk_fma_f32 %[t1], %[pe23], %[n1], %[be]\n\t"
            "v_pk_fma_f32 %[t2], %[pp23], %[n1], %[bp]\n\t"
            "v_pk_mul_f32 %[t1], %[t1], %[t1]\n\t"
            "v_pk_mul_f32 %[t2], %[t2], %[t2]\n\t"
            "v_pk_add_f32 %[t1], %[t1], %[t2]\n\t"
            "v_pk_mul_f32 %[t1], %[t1], %[bw]\n\t"
            "v_pk_add_f32 %[acc], %[acc], %[t1]\n\t"
            : [t1] "=&v"(t1), [t2] "=&v"(t2), [acc] "+v"(c.acc23),
              [bw] "+v"(c.bw[S]), [be] "+v"(c.be[S]), [bp] "+v"(c.bp[S])
            : [pe23] "v"(c.pe23), [pp23] "v"(c.pp23), [n1] "v"(c.n1), [K] "i"(K));
        if constexpr (G == 7) {  // s1@7, unpredicated, np scalar order
            const float de = __fsub_rn(c.be[S].x, c.pe1);
            const float dp = __fsub_rn(c.bp[S].x, c.pp1);
            const float r2 = __fadd_rn(__fmul_rn(de, de), __fmul_rn(dp, dp));
            c.a1 = __fadd_rn(c.a1, __fmul_rn(r2, c.bw[S].x));
        }
    } else if constexpr (G <= 134) {
        if constexpr (G == 72) { c.accM.x = c.a1; c.accM.y = c.acc23.y; }
        // accM = [a1 (s1 pred, live iff lane >= G-71), a3 (s3 unpred)].
        // Compile-time lane mask -> vcc via SALU (hidden); single cndmask.
        constexpr unsigned sh = G - 71;  // live lanes: lane >= sh, sh in 1..63
        constexpr unsigned lm = sh < 32 ? (0xFFFFFFFFu << sh) : 0u;
        constexpr unsigned hm = sh < 32 ? 0xFFFFFFFFu : (0xFFFFFFFFu << (sh - 32));
        asm volatile(
            "s_waitcnt lgkmcnt(%c[K])\n\t"
            "v_pk_fma_f32 v[40:41], %[pe13], %[n1], %[be]\n\t"
            "v_pk_fma_f32 v[42:43], %[pp13], %[n1], %[bp]\n\t"
            "s_mov_b32 vcc_lo, %c[LM]\n\t"
            "s_mov_b32 vcc_hi, %c[HM]\n\t"
            "v_pk_mul_f32 v[40:41], v[40:41], v[40:41]\n\t"
            "v_pk_mul_f32 v[42:43], v[42:43], v[42:43]\n\t"
            "v_pk_add_f32 v[40:41], v[40:41], v[42:43]\n\t"
            "v_pk_mul_f32 v[40:41], v[40:41], %[bw]\n\t"
            "v_cndmask_b32 v40, 0, v40, vcc\n\t"
            "v_pk_add_f32 %[acc], %[acc], v[40:41]\n\t"
            : [acc] "+v"(c.accM), [bw] "+v"(c.bw[S]), [be] "+v"(c.be[S]),
              [bp] "+v"(c.bp[S])
            : [pe13] "v"(c.pe13), [pp13] "v"(c.pp13), [n1] "v"(c.n1),
              [K] "i"(K), [LM] "i"(lm), [HM] "i"(hm)
            : "v40", "v41", "v42", "v43", "vcc");
    } else if constexpr (G == 135) {
        asm volatile("s_waitcnt lgkmcnt(%c[K])"
                     : [bw] "+v"(c.bw[S]), [be] "+v"(c.be[S]), [bp] "+v"(c.bp[S])
                     : [K] "i"(K));
        const float de = __fsub_rn(c.be[S].x, c.pe3);
        const float dp = __fsub_rn(c.bp[S].x, c.pp3);
        const float r2 = __fadd_rn(__fmul_rn(de, de), __fmul_rn(dp, dp));
        c.accM.y = __fadd_rn(c.accM.y, __fmul_rn(r2, c.bw[S].x));
    } else {
        if constexpr (G == 136) { c.accY.x = c.acc23.x; c.accY.y = c.accM.y; }
        constexpr unsigned sh = G - 135;  // v+1, 1..63; active lanes: lane > v
        constexpr unsigned lm = sh < 32 ? (0xFFFFFFFFu << sh) : 0u;
        constexpr unsigned hm = sh < 32 ? 0xFFFFFFFFu : (0xFFFFFFFFu << (sh - 32));
        f2 t1, t2;
        asm volatile(
            "s_waitcnt lgkmcnt(%c[K])\n\t"
            "s_mov_b32 exec_lo, %c[LM]\n\t"
            "s_mov_b32 exec_hi, %c[HM]\n\t"
            "v_pk_fma_f32 %[t1], %[pe23], %[n1], %[be]\n\t"
            "v_pk_fma_f32 %[t2], %[pp23], %[n1], %[bp]\n\t"
            "v_pk_mul_f32 %[t1], %[t1], %[t1]\n\t"
            "v_pk_mul_f32 %[t2], %[t2], %[t2]\n\t"
            "v_pk_add_f32 %[t1], %[t1], %[t2]\n\t"
            "v_pk_mul_f32 %[t1], %[t1], %[bw]\n\t"
            "v_pk_add_f32 %[acc], %[acc], %[t1]\n\t"
            "s_mov_b64 exec, -1\n\t"
            : [t1] "=&v"(t1), [t2] "=&v"(t2), [acc] "+v"(c.accY),
              [bw] "+v"(c.bw[S]), [be] "+v"(c.be[S]), [bp] "+v"(c.bp[S])
            : [pe23] "v"(c.pe23), [pp23] "v"(c.pp23), [n1] "v"(c.n1),
              [K] "i"(K), [LM] "i"(lm), [HM] "i"(hm));
    }
}

template <int G>
__device__ __forceinline__ void run(Ctx& c) {
    if constexpr (G <= 198) {
        cstep<G>(c);
        // t_j staging hooks (lgkm-safe: extra outstanding write only makes
        // later counted waits more conservative).
        if constexpr (G == 6) {   // t0 final (s0 has only i=0..6)
            c.l2[c.lane] = __fmul_rn(c.pw0, c.a0);  // lanes>=8 garbage, overwritten
        }
        if constexpr (G == 134) { // t1 final (s1 pred ends at i=134-64=70)
            c.l2[8 + c.lane] = __fmul_rn(c.pw1, c.accM.x);
        }
        if constexpr (G + 5 <= 198) prefetch<G + 5>(c);
        run<G + 1>(c);
    }
}

__global__ __launch_bounds__(64) void jet_ecf_kernel(const float* __restrict__ x,
                                                     float* __restrict__ out,
                                                     int njet) {
#pragma clang fp contract(off)
    const int jet = blockIdx.x;
    if (jet >= njet) return;
    const int lane = threadIdx.x;
    const float* xj = x + (size_t)jet * NPART * 3;

    __shared__ float lds[600];                  // SoA: w, e, p
    __shared__ __align__(16) float lds2[200];   // t_j staging for e2f

    // Slot register loads: slot0: j=lane (lanes 0..7), slot1: j=8+lane,
    // slot2: j=72+lane, slot3: j=136+lane. Dummy lanes zero-padded.
    float pw[4], pea[4], ppa[4];
    {
        const int base[4] = {0, 8, 72, 136};
        #pragma unroll
        for (int k = 0; k < 4; ++k) {
            const int p = base[k] + lane;
            const bool valid = (k > 0) || (lane < 8);
            if (valid) {
                pw[k] = xj[p * 3 + 0];
                pea[k] = xj[p * 3 + 1];
                ppa[k] = xj[p * 3 + 2];
            } else {
                pw[k] = 0.0f; pea[k] = 0.0f; ppa[k] = 0.0f;
            }
        }
    }

    // LDS staging of i-side values.
    #pragma unroll
    for (int r = 0; r < 4; ++r) {
        const int i = lane + (r << 6);
        if (i < NPART) {
            lds[i]       = xj[3 * i + 0];
            lds[200 + i] = xj[3 * i + 1];
            lds[400 + i] = xj[3 * i + 2];
        }
    }

    // Pin staging stores before Phase B's asm reads them (block = 1 wave, so
    // no barrier needed — just an explicit drain + compiler memory fence).
    asm volatile("" ::: "memory");
    __builtin_amdgcn_sched_barrier(0);
    asm volatile("s_waitcnt lgkmcnt(0)" ::: "memory");

    // ---- Phase B: np-order fp32 column sums, packed 2-wide.
    Ctx c;
    c.lane = lane;
    c.aw = (unsigned)(uintptr_t)&lds[0];
    c.ae = (unsigned)(uintptr_t)&lds[200];
    c.ap = (unsigned)(uintptr_t)&lds[400];
    c.l2 = lds2;
    c.pw0 = pw[0]; c.pw1 = pw[1];
    c.n1.x = -1.0f; c.n1.y = -1.0f;
    c.pe01.x = pea[0]; c.pe01.y = pea[1];
    c.pp01.x = ppa[0]; c.pp01.y = ppa[1];
    c.pe23.x = pea[2]; c.pe23.y = pea[3];
    c.pp23.x = ppa[2]; c.pp23.y = ppa[3];
    c.pe13.x = pea[1]; c.pe13.y = pea[3];
    c.pp13.x = ppa[1]; c.pp13.y = ppa[3];
    c.pe1 = pea[1]; c.pp1 = ppa[1]; c.pe3 = pea[3]; c.pp3 = ppa[3];
    c.acc23.x = 0.0f; c.acc23.y = 0.0f;
    c.accY.x = 0.0f;  c.accY.y = 0.0f;
    c.accM.x = 0.0f;  c.accM.y = 0.0f;
    c.tt.x = 0.0f;    c.tt.y = 0.0f;
    c.a0 = c.a1 = 0.0f;
    #pragma unroll
    for (int k = 0; k < 5; ++k) {
        c.bw[k].x = 0.0f; c.bw[k].y = 0.0f;
        c.be[k].x = 0.0f; c.be[k].y = 0.0f;
        c.bp[k].x = 0.0f; c.bp[k].y = 0.0f;
    }

    prefetch<0>(c); prefetch<1>(c); prefetch<2>(c); prefetch<3>(c); prefetch<4>(c);
    run<0>(c);

    // Final t stores: t2 = pw2*s2, t3 = pw3*s3 (finals in accY).
    lds2[72 + lane]  = __fmul_rn(pw[2], c.accY.x);
    lds2[136 + lane] = __fmul_rn(pw[3], c.accY.y);

    // ---- Phase A (post-B): exact fp64 moments. fp64 oracle; explicit fma()
    // since contract(off). Pure VALU — issues while lds2 writes drain.
    double S = 0, Sa = 0, Se = 0, Sp = 0, Saa = 0;
    double Sae = 0, Sap = 0, See = 0, Spp = 0, Sep = 0;
    #pragma unroll
    for (int k = 0; k < 4; ++k) {
        const double w = (double)pw[k];
        const double e = (double)pea[k];
        const double f = (double)ppa[k];
        const double a = fma(f, f, e * e);
        const double wa = w * a, we = w * e, wf = w * f;
        S += w; Sa += wa; Se += we; Sp += wf;
        Saa = fma(wa, a, Saa);
        Sae = fma(wa, e, Sae);
        Sap = fma(wa, f, Sap);
        See = fma(we, e, See);
        Sep = fma(we, f, Sep);
        Spp = fma(wf, f, Spp);
    }

    // Fence: all lds2 writes (hooks + finals) complete before float4 reads.
    asm volatile("s_waitcnt lgkmcnt(0)" ::: "memory");

    // ecf2 = sum_j fl(pt_j*s_j), sequential ascending j — identical values
    // and order to before. 200-add chain interleaved with the 6-level shfl
    // reduction (independent chains, different pipes): wall = max not sum.
    float e2f = 0.0f;
    const float4* lt = reinterpret_cast<const float4*>(lds2);
#define QUAD(Q)                                                               \
    {                                                                         \
        const float4 v = lt[Q];                                               \
        e2f = __fadd_rn(e2f, v.x);                                            \
        e2f = __fadd_rn(e2f, v.y);                                            \
        e2f = __fadd_rn(e2f, v.z);                                            \
        e2f = __fadd_rn(e2f, v.w);                                            \
    }
#define QUADS8(B)                                                             \
    QUAD(B) QUAD(B + 1) QUAD(B + 2) QUAD(B + 3)                               \
    QUAD(B + 4) QUAD(B + 5) QUAD(B + 6) QUAD(B + 7)
#define RED(OFF)                                                              \
    S   += __shfl_down(S,   OFF, 64);                                         \
    Sa  += __shfl_down(Sa,  OFF, 64);                                         \
    Se  += __shfl_down(Se,  OFF, 64);                                         \
    Sp  += __shfl_down(Sp,  OFF, 64);                                         \
    Saa += __shfl_down(Saa, OFF, 64);                                         \
    Sae += __shfl_down(Sae, OFF, 64);                                         \
    Sap += __shfl_down(Sap, OFF, 64);                                         \
    See += __shfl_down(See, OFF, 64);                                         \
    Spp += __shfl_down(Spp, OFF, 64);                                         \
    Sep += __shfl_down(Sep, OFF, 64);

    QUADS8(0)   RED(32)
    QUADS8(8)   RED(16)
    QUADS8(16)  RED(8)
    QUADS8(24)  RED(4)
    QUADS8(32)  RED(2)
    QUADS8(40)  RED(1)
    QUAD(48) QUAD(49)
#undef QUAD
#undef QUADS8
#undef RED

    if (lane == 0) {
        // ecf3 = T/6, T = sum_{b,g} ab[b][g] C[b][g]. A's rows are signed
        // perms of B's rows (A0=B1, A1=B0, A2=-2B2, A3=-2B3), so
        // ab[b][g] = R1bR0g + R0bR1g - 2R2bR2g - 2R3bR3g  (symmetric),
        // T = D + 2U over symmetric C. fp64 oracle: reordering legal.
        const double nSe2 = -2.0 * Se,  nSp2 = -2.0 * Sp;
        const double nSae2 = -2.0 * Sae, nSap2 = -2.0 * Sap;
        const double nSee2 = -2.0 * See, nSep2 = -2.0 * Sep, nSpp2 = -2.0 * Spp;
        const double p4See = -2.0 * nSee2, p4Sep = -2.0 * nSep2,
                     p4Spp = -2.0 * nSpp2;
        const double R0[4]  = { Sa,    S,    nSe2,  nSp2  };
        const double R1[4]  = { Saa,   Sa,   nSae2, nSap2 };
        const double R2[4]  = { Sae,   Se,   nSee2, nSep2 };
        const double R3[4]  = { Sap,   Sp,   nSep2, nSpp2 };
        const double R2s[4] = { nSae2, nSe2, p4See, p4Sep };   // -2*R2
        const double R3s[4] = { nSap2, nSp2, p4Sep, p4Spp };   // -2*R3
        double Gm[4][4];
        #pragma unroll
        for (int b = 0; b < 4; ++b) {
            #pragma unroll
            for (int g = b; g < 4; ++g) {
                double t = R1[b] * R0[g];
                t = fma(R0[b],  R1[g], t);
                t = fma(R2s[b], R2[g], t);
                t = fma(R3s[b], R3[g], t);
                Gm[b][g] = t;
            }
        }
        double D = Gm[0][0] * S;                 // C diag: S, Saa, See, Spp
        D = fma(Gm[1][1], Saa, D);
        D = fma(Gm[2][2], See, D);
        D = fma(Gm[3][3], Spp, D);
        double U = Gm[0][1] * Sa;                // C offdiag: Sa,Se,Sp,Sae,Sap,Sep
        U = fma(Gm[0][2], Se,  U);
        U = fma(Gm[0][3], Sp,  U);
        U = fma(Gm[1][2], Sae, U);
        U = fma(Gm[1][3], Sap, U);
        U = fma(Gm[2][3], Sep, U);
        const double T = fma(2.0, U, D);
        const double ecf1 = S;
        const double ecf2 = (double)e2f;
        const double ecf3 = T * (1.0 / 6.0);
        const double d2 = ecf3 * ecf1 * ecf1 * ecf1 / (ecf2 * ecf2 * ecf2 + 1e-7);
        float4 o = make_float4((float)ecf1, (float)ecf2, (float)ecf3, (float)d2);
        *reinterpret_cast<float4*>(out + (size_t)jet * 4) = o;
    }
}

extern "C" void kernel_launch(void* const* d_in, const int* in_sizes, int n_in,
                              void* d_out, int out_size, void* d_ws, size_t ws_size,
                              hipStream_t stream) {
    const float* x = (const float*)d_in[0];
    float* out = (float*)d_out;
    const int njet = in_sizes[0] / (NPART * 3);
    jet_ecf_kernel<<<njet, 64, 0, stream>>>(x, out, njet);
}